// Round 10
// baseline (119.603 us; speedup 1.0000x reference)
//
#include <hip/hip_runtime.h>
#include <stdint.h>

// Group / KNN: B=16, N=16384, NUM_GROUP=512, GROUP_SIZE=32.
// d_out = neighborhood [16][512][32][3] ++ center [16][512][3] ++ ids [16][512]
//
// r10 = r9 skeleton (GB=8 groups/block, two passes over LDS-staged 2048-pt
// tiles, async-stage split, float thresholds, counting-sort ranking) with:
//  (1) LDS cut below the 4-blocks/CU cliff: candidate buffer split into
//      u32 key + u16 idx arrays (10.75 KB vs 14.3 KB u64) -> ~36.6 KB total
//      (r9's 40448 B left only 2 KB slack for 4 blocks -> was 2-3 resident).
//  (2) csq dropped from the hot loop: within a group, ranking by
//      s = xs - 2c.x  ==  ranking by |x-c|^2 (outputs never use sqr);
//      43 -> 35 VALU ops/point.
//  (3) block-uniform center constants moved to SGPRs via readfirstlane.
// Ranking ties broken by lower point index via lexicographic (key, idx).

#define TB     512
#define GB     8                  // groups per block
#define TP     2048               // points per LDS tile
#define NT     (16384 / TP)       // 8 tiles
#define PPTILE (TP / TB)          // 4 points per thread per tile
#define NWAVE  (TB / 64)          // 8
#define CAP    224                // per-group candidate capacity

__device__ __forceinline__ float rfl(float v) {
    return __uint_as_float(__builtin_amdgcn_readfirstlane(__float_as_uint(v)));
}

__global__ __launch_bounds__(TB) void group_knn_kernel(
    const float* __restrict__ xyz,   // [16][16384][3]
    float* __restrict__ out_nb,      // [16][512][32][3]
    float* __restrict__ out_ctr,     // [16][512][3]
    float* __restrict__ out_ids)     // [16][512]
{
    const int NPTS = 16384;
    const int GSZ  = 32;

    const int blk = blockIdx.x;            // 0 .. 1023
    const int b   = blk >> 6;              // 64 blocks per batch
    const int g0  = (blk & 63) * GB;       // first group of this block
    const int t   = threadIdx.x;
    const int lane = t & 63;
    const int w    = t >> 6;

    const float* base = xyz + (size_t)b * NPTS * 3;

    // Per-group constants -> SGPRs (block-uniform).
    float n2c0[GB], n2c1[GB], n2c2[GB];
#pragma unroll
    for (int q = 0; q < GB; ++q) {
        const int nc = (g0 + q) * 32;
        n2c0[q] = rfl(-2.0f * base[nc * 3 + 0]);
        n2c1[q] = rfl(-2.0f * base[nc * 3 + 1]);
        n2c2[q] = rfl(-2.0f * base[nc * 3 + 2]);
    }

    __shared__ float s_pts[TP * 3];                    // 24576 B
    __shared__ unsigned s_key[GB][CAP];                //  7168 B
    __shared__ unsigned short s_idx[GB][CAP];          //  3584 B
    __shared__ float s_t[GB][NWAVE];                   //   256 B
    __shared__ int s_cnt[GB];                          //    32 B
    __shared__ unsigned s_win[GB][GSZ];                //  1024 B

    const float4* gall = (const float4*)base;          // 12288 float4
    float4* l4 = (float4*)s_pts;

    float4 r0, r1, r2;                                 // staging registers

    // ---- Pass A: per-thread float min per group -------------------------
    float m[GB];
#pragma unroll
    for (int q = 0; q < GB; ++q) m[q] = __builtin_inff();

    r0 = gall[0 * 1536 + 0 * TB + t];
    r1 = gall[0 * 1536 + 1 * TB + t];
    r2 = gall[0 * 1536 + 2 * TB + t];

    for (int tile = 0; tile < NT; ++tile) {
        __syncthreads();                   // prior readers done
        l4[0 * TB + t] = r0;
        l4[1 * TB + t] = r1;
        l4[2 * TB + t] = r2;
        __syncthreads();                   // buf visible
        if (tile + 1 < NT) {               // issue next tile's loads (overlap)
            r0 = gall[(tile + 1) * 1536 + 0 * TB + t];
            r1 = gall[(tile + 1) * 1536 + 1 * TB + t];
            r2 = gall[(tile + 1) * 1536 + 2 * TB + t];
        }
#pragma unroll
        for (int k = 0; k < PPTILE; ++k) {
            const int l = k * TB + t;
            const float x0 = s_pts[l * 3 + 0];
            const float x1 = s_pts[l * 3 + 1];
            const float x2 = s_pts[l * 3 + 2];
            const float xs = __builtin_fmaf(x2, x2, __builtin_fmaf(x1, x1, x0 * x0));
#pragma unroll
            for (int q = 0; q < GB; ++q) {
                const float s = __builtin_fmaf(n2c0[q], x0,
                                __builtin_fmaf(n2c1[q], x1,
                                __builtin_fmaf(n2c2[q], x2, xs)));
                m[q] = fminf(m[q], s);
            }
        }
    }

    // prefetch pass-B tile 0 (hides under threshold phase)
    r0 = gall[0 * 1536 + 0 * TB + t];
    r1 = gall[0 * 1536 + 1 * TB + t];
    r2 = gall[0 * 1536 + 2 * TB + t];

    // ---- Thresholds: per-wave float bitonic; T_g = max of 4th-smallest --
#pragma unroll
    for (int q = 0; q < GB; ++q) {
        float v = m[q];
#pragma unroll
        for (int k = 2; k <= 64; k <<= 1) {
#pragma unroll
            for (int j = k >> 1; j > 0; j >>= 1) {
                const float o = __shfl_xor(v, j, 64);
                const bool up = ((lane & k) == 0);
                const bool takeMin = (((lane & j) == 0) == up);
                const float mn = fminf(v, o);
                const float mx = fmaxf(v, o);
                v = takeMin ? mn : mx;
            }
        }
        if (lane == 3) s_t[q][w] = v;    // 4th smallest in this wave
    }
    if (t < GB) s_cnt[t] = 0;
    __syncthreads();

    float T[GB];
#pragma unroll
    for (int q = 0; q < GB; ++q) {
        float Tq = s_t[q][0];
#pragma unroll
        for (int ww = 1; ww < NWAVE; ++ww) Tq = fmaxf(Tq, s_t[q][ww]);
        T[q] = Tq;
    }

    // ---- Pass B: recompute, collect keys for s <= T_g -------------------
    for (int tile = 0; tile < NT; ++tile) {
        __syncthreads();
        l4[0 * TB + t] = r0;
        l4[1 * TB + t] = r1;
        l4[2 * TB + t] = r2;
        __syncthreads();
        if (tile + 1 < NT) {
            r0 = gall[(tile + 1) * 1536 + 0 * TB + t];
            r1 = gall[(tile + 1) * 1536 + 1 * TB + t];
            r2 = gall[(tile + 1) * 1536 + 2 * TB + t];
        }
#pragma unroll
        for (int k = 0; k < PPTILE; ++k) {
            const int l = k * TB + t;
            const int n = tile * TP + l;
            const float x0 = s_pts[l * 3 + 0];
            const float x1 = s_pts[l * 3 + 1];
            const float x2 = s_pts[l * 3 + 2];
            const float xs = __builtin_fmaf(x2, x2, __builtin_fmaf(x1, x1, x0 * x0));
#pragma unroll
            for (int q = 0; q < GB; ++q) {
                const float s = __builtin_fmaf(n2c0[q], x0,
                                __builtin_fmaf(n2c1[q], x1,
                                __builtin_fmaf(n2c2[q], x2, xs)));
                if (s <= T[q]) {
                    unsigned u = __float_as_uint(s);
                    u ^= (unsigned)(((int)u) >> 31) | 0x80000000u;
                    const int pos = atomicAdd(&s_cnt[q], 1);
                    if (pos < CAP) {
                        s_key[q][pos] = u;
                        s_idx[q][pos] = (unsigned short)n;
                    }
                }
            }
        }
    }
    __syncthreads();

    // ---- Ranking: wave w handles group w --------------------------------
    {
        const int q = w;
        const int cnt = s_cnt[q];
        if (cnt <= CAP) {
            // counting sort, lexicographic (key, idx): exact, ties to lower n
            for (int j = lane; j < cnt; j += 64) {
                const unsigned cu = s_key[q][j];
                const unsigned short cn = s_idx[q][j];
                int r = 0;
                for (int i = 0; i < cnt; ++i) {
                    const unsigned ui = s_key[q][i];
                    r += (ui < cu || (ui == cu && s_idx[q][i] < cn)) ? 1 : 0;
                }
                if (r < GSZ) s_win[q][r] = cn;
            }
        } else {
            // Wave-parallel exact fallback (statistically unreachable).
            unsigned long long last = 0ull;
            for (int k = 0; k < GSZ; ++k) {
                unsigned long long best = ~0ull;
                for (int n = lane; n < NPTS; n += 64) {
                    const float x0 = base[n * 3 + 0];
                    const float x1 = base[n * 3 + 1];
                    const float x2 = base[n * 3 + 2];
                    const float xs = __builtin_fmaf(x2, x2,
                                     __builtin_fmaf(x1, x1, x0 * x0));
                    const float s = __builtin_fmaf(n2c0[q], x0,
                                    __builtin_fmaf(n2c1[q], x1,
                                    __builtin_fmaf(n2c2[q], x2, xs)));
                    unsigned u = __float_as_uint(s);
                    u ^= (unsigned)(((int)u) >> 31) | 0x80000000u;
                    const unsigned long long kk =
                        ((unsigned long long)u << 32) | (unsigned)n;
                    if (kk > last && kk < best) best = kk;
                }
#pragma unroll
                for (int mm = 32; mm >= 1; mm >>= 1) {
                    const unsigned long long o = __shfl_xor(best, mm, 64);
                    best = (o < best) ? o : best;
                }
                last = best;
                if (lane == 0) s_win[q][k] = (unsigned)best & 0xFFFFu;
            }
        }
    }
    __syncthreads();

    // ---- Outputs --------------------------------------------------------
    const int gbase = b * 512 + g0;
    if (t < GB * GSZ) {                       // 256 threads: neighborhoods
        const int q  = t >> 5;
        const int tt = t & 31;
        const int nc = (g0 + q) * 32;
        const float cc0 = base[nc * 3 + 0];
        const float cc1 = base[nc * 3 + 1];
        const float cc2 = base[nc * 3 + 2];
        const unsigned n = s_win[q][tt];
        const float x0 = base[n * 3 + 0];
        const float x1 = base[n * 3 + 1];
        const float x2 = base[n * 3 + 2];
        const size_t ob = (((size_t)(gbase + q)) * GSZ + tt) * 3;
        out_nb[ob + 0] = x0 - cc0;
        out_nb[ob + 1] = x1 - cc1;
        out_nb[ob + 2] = x2 - cc2;
    } else if (t < GB * GSZ + GB * 3) {       // 24 threads: centers
        const int u = t - GB * GSZ;
        const int q = u / 3, c = u % 3;
        out_ctr[(size_t)(gbase + q) * 3 + c] = base[((g0 + q) * 32) * 3 + c];
    } else if (t < GB * GSZ + GB * 3 + GB) {  // 8 threads: ids
        const int q = t - (GB * GSZ + GB * 3);
        out_ids[gbase + q] = (float)((g0 + q) * 32);
    }
}

extern "C" void kernel_launch(void* const* d_in, const int* in_sizes, int n_in,
                              void* d_out, int out_size, void* d_ws, size_t ws_size,
                              hipStream_t stream) {
    const float* xyz = (const float*)d_in[0];
    float* out = (float*)d_out;
    float* out_nb  = out;                        // 786432
    float* out_ctr = out + 786432;               // 24576
    float* out_ids = out + 786432 + 24576;       // 8192
    hipLaunchKernelGGL(group_knn_kernel, dim3(16 * 512 / GB), dim3(TB), 0, stream,
                       xyz, out_nb, out_ctr, out_ids);
}

// Round 11
// 76.253 us; speedup vs baseline: 1.5685x; 1.5685x over previous
//
#include <hip/hip_runtime.h>
#include <stdint.h>

// Group / KNN: B=16, N=16384, NUM_GROUP=512, GROUP_SIZE=32.
// d_out = neighborhood [16][512][32][3] ++ center [16][512][3] ++ ids [16][512]
//
// r11: r9's algorithm (GB=8 groups/block, two passes, float thresholds via
// per-wave bitonic of lane minima, u64 counting-sort ranking) with the LDS
// data path REMOVED. r7-r10 showed the tile loop's block-wide lockstep
// (32x {barrier, ds_write, barrier}) was pure stall: staged data has zero
// reuse (read once), and the 3 MB input is L2-resident. Both passes read
// points directly from global as dwordx3 (12 B/lane contiguous = 768 B per
// wave instruction, coalesced). Hot path has NO barriers (3 total in kernel).
// Scoring (csq-less, same as r10): s = fma(n2c0,x0, fma(n2c1,x1,
// fma(n2c2,x2, xs))) — rank-equivalent to |x-c|^2 within a group.

#define TB     512
#define GB     8                  // groups per block
#define PPT    32                 // points per thread = 16384/TB
#define NWAVE  (TB / 64)          // 8
#define CAP    224                // per-group candidate capacity

__global__ __launch_bounds__(TB) void group_knn_kernel(
    const float* __restrict__ xyz,   // [16][16384][3]
    float* __restrict__ out_nb,      // [16][512][32][3]
    float* __restrict__ out_ctr,     // [16][512][3]
    float* __restrict__ out_ids)     // [16][512]
{
    const int NPTS = 16384;
    const int GSZ  = 32;

    const int blk = blockIdx.x;            // 0 .. 1023
    const int b   = blk >> 6;              // 64 blocks per batch
    const int g0  = (blk & 63) * GB;       // first group of this block
    const int t   = threadIdx.x;
    const int lane = t & 63;
    const int w    = t >> 6;

    const float* base = xyz + (size_t)b * NPTS * 3;

    // Per-group constants (block-uniform; L1-broadcast loads).
    float n2c0[GB], n2c1[GB], n2c2[GB];
#pragma unroll
    for (int q = 0; q < GB; ++q) {
        const int nc = (g0 + q) * 32;
        n2c0[q] = -2.0f * base[nc * 3 + 0];
        n2c1[q] = -2.0f * base[nc * 3 + 1];
        n2c2[q] = -2.0f * base[nc * 3 + 2];
    }

    __shared__ unsigned long long s_cand[GB][CAP];     // 14336 B
    __shared__ float s_t[GB][NWAVE];                   //   256 B
    __shared__ int s_cnt[GB];                          //    32 B
    __shared__ unsigned s_win[GB][GSZ];                //  1024 B

    // ---- Pass A: per-thread float min per group (direct global reads) ---
    float m[GB];
#pragma unroll
    for (int q = 0; q < GB; ++q) m[q] = __builtin_inff();

    for (int i = 0; i < PPT; i += 4) {
        float px[4][3];
#pragma unroll
        for (int u = 0; u < 4; ++u) {              // 4 dwordx3 loads in flight
            const int n = (i + u) * TB + t;
            const float* p = base + (size_t)n * 3;
            px[u][0] = p[0]; px[u][1] = p[1]; px[u][2] = p[2];
        }
#pragma unroll
        for (int u = 0; u < 4; ++u) {
            const float x0 = px[u][0], x1 = px[u][1], x2 = px[u][2];
            const float xs = __builtin_fmaf(x2, x2, __builtin_fmaf(x1, x1, x0 * x0));
#pragma unroll
            for (int q = 0; q < GB; ++q) {
                const float s = __builtin_fmaf(n2c0[q], x0,
                                __builtin_fmaf(n2c1[q], x1,
                                __builtin_fmaf(n2c2[q], x2, xs)));
                m[q] = fminf(m[q], s);
            }
        }
    }

    // ---- Thresholds: per-wave float bitonic; T_g = max of 4th-smallest --
#pragma unroll
    for (int q = 0; q < GB; ++q) {
        float v = m[q];
#pragma unroll
        for (int k = 2; k <= 64; k <<= 1) {
#pragma unroll
            for (int j = k >> 1; j > 0; j >>= 1) {
                const float o = __shfl_xor(v, j, 64);
                const bool up = ((lane & k) == 0);
                const bool takeMin = (((lane & j) == 0) == up);
                const float mn = fminf(v, o);
                const float mx = fmaxf(v, o);
                v = takeMin ? mn : mx;
            }
        }
        if (lane == 3) s_t[q][w] = v;    // 4th smallest in this wave
    }
    if (t < GB) s_cnt[t] = 0;
    __syncthreads();                                   // barrier 1

    float T[GB];
#pragma unroll
    for (int q = 0; q < GB; ++q) {
        float Tq = s_t[q][0];
#pragma unroll
        for (int ww = 1; ww < NWAVE; ++ww) Tq = fmaxf(Tq, s_t[q][ww]);
        T[q] = Tq;
    }

    // ---- Pass B: recompute (L2-hot), collect keys for s <= T_g ----------
    for (int i = 0; i < PPT; i += 4) {
        float px[4][3];
#pragma unroll
        for (int u = 0; u < 4; ++u) {
            const int n = (i + u) * TB + t;
            const float* p = base + (size_t)n * 3;
            px[u][0] = p[0]; px[u][1] = p[1]; px[u][2] = p[2];
        }
#pragma unroll
        for (int u = 0; u < 4; ++u) {
            const int n = (i + u) * TB + t;
            const float x0 = px[u][0], x1 = px[u][1], x2 = px[u][2];
            const float xs = __builtin_fmaf(x2, x2, __builtin_fmaf(x1, x1, x0 * x0));
#pragma unroll
            for (int q = 0; q < GB; ++q) {
                const float s = __builtin_fmaf(n2c0[q], x0,
                                __builtin_fmaf(n2c1[q], x1,
                                __builtin_fmaf(n2c2[q], x2, xs)));
                if (s <= T[q]) {
                    unsigned uu = __float_as_uint(s);
                    uu ^= (unsigned)(((int)uu) >> 31) | 0x80000000u;
                    const int pos = atomicAdd(&s_cnt[q], 1);
                    if (pos < CAP)
                        s_cand[q][pos] = ((unsigned long long)uu << 32) | (unsigned)n;
                }
            }
        }
    }
    __syncthreads();                                   // barrier 2

    // ---- Ranking: wave w handles group w --------------------------------
    {
        const int q = w;
        const int cnt = s_cnt[q];
        if (cnt <= CAP) {
            // counting sort (keys unique; broadcast inner reads)
            for (int j = lane; j < cnt; j += 64) {
                const unsigned long long c = s_cand[q][j];
                int r = 0;
                for (int i = 0; i < cnt; ++i) r += (s_cand[q][i] < c) ? 1 : 0;
                if (r < GSZ) s_win[q][r] = (unsigned)c & 0xFFFFu;
            }
        } else {
            // Wave-parallel exact fallback (statistically unreachable).
            unsigned long long last = 0ull;
            for (int k = 0; k < GSZ; ++k) {
                unsigned long long best = ~0ull;
                for (int n = lane; n < NPTS; n += 64) {
                    const float x0 = base[n * 3 + 0];
                    const float x1 = base[n * 3 + 1];
                    const float x2 = base[n * 3 + 2];
                    const float xs = __builtin_fmaf(x2, x2,
                                     __builtin_fmaf(x1, x1, x0 * x0));
                    const float s = __builtin_fmaf(n2c0[q], x0,
                                    __builtin_fmaf(n2c1[q], x1,
                                    __builtin_fmaf(n2c2[q], x2, xs)));
                    unsigned uu = __float_as_uint(s);
                    uu ^= (unsigned)(((int)uu) >> 31) | 0x80000000u;
                    const unsigned long long kk =
                        ((unsigned long long)uu << 32) | (unsigned)n;
                    if (kk > last && kk < best) best = kk;
                }
#pragma unroll
                for (int mm = 32; mm >= 1; mm >>= 1) {
                    const unsigned long long o = __shfl_xor(best, mm, 64);
                    best = (o < best) ? o : best;
                }
                last = best;
                if (lane == 0) s_win[q][k] = (unsigned)best & 0xFFFFu;
            }
        }
    }
    __syncthreads();                                   // barrier 3

    // ---- Outputs --------------------------------------------------------
    const int gbase = b * 512 + g0;
    if (t < GB * GSZ) {                       // 256 threads: neighborhoods
        const int q  = t >> 5;
        const int tt = t & 31;
        const int nc = (g0 + q) * 32;
        const float cc0 = base[nc * 3 + 0];
        const float cc1 = base[nc * 3 + 1];
        const float cc2 = base[nc * 3 + 2];
        const unsigned n = s_win[q][tt];
        const float x0 = base[n * 3 + 0];
        const float x1 = base[n * 3 + 1];
        const float x2 = base[n * 3 + 2];
        const size_t ob = (((size_t)(gbase + q)) * GSZ + tt) * 3;
        out_nb[ob + 0] = x0 - cc0;
        out_nb[ob + 1] = x1 - cc1;
        out_nb[ob + 2] = x2 - cc2;
    } else if (t < GB * GSZ + GB * 3) {       // 24 threads: centers
        const int u = t - GB * GSZ;
        const int q = u / 3, c = u % 3;
        out_ctr[(size_t)(gbase + q) * 3 + c] = base[((g0 + q) * 32) * 3 + c];
    } else if (t < GB * GSZ + GB * 3 + GB) {  // 8 threads: ids
        const int q = t - (GB * GSZ + GB * 3);
        out_ids[gbase + q] = (float)((g0 + q) * 32);
    }
}

extern "C" void kernel_launch(void* const* d_in, const int* in_sizes, int n_in,
                              void* d_out, int out_size, void* d_ws, size_t ws_size,
                              hipStream_t stream) {
    const float* xyz = (const float*)d_in[0];
    float* out = (float*)d_out;
    float* out_nb  = out;                        // 786432
    float* out_ctr = out + 786432;               // 24576
    float* out_ids = out + 786432 + 24576;       // 8192
    hipLaunchKernelGGL(group_knn_kernel, dim3(16 * 512 / GB), dim3(TB), 0, stream,
                       xyz, out_nb, out_ctr, out_ids);
}